// Round 3
// baseline (178.009 us; speedup 1.0000x reference)
//
#include <hip/hip_runtime.h>
#include <hip/hip_bf16.h>

// Problem constants (fixed by setup_inputs)
#define B_ 8
#define N_ 16384
#define C_ 64
#define S_ 5

typedef float v4f __attribute__((ext_vector_type(4)));
typedef __bf16 v8bf __attribute__((ext_vector_type(8)));

// fp32 -> bf16 bits, round-to-nearest-even (finite inputs only)
static __device__ __forceinline__ unsigned short f2bf(float f) {
    unsigned int u = __float_as_uint(f);
    u += 0x7fffu + ((u >> 16) & 1u);
    return (unsigned short)(u >> 16);
}

// constant-folding accessor into a float4 array (unrolled loops only)
#define GETF(A, i) (((i) & 3) == 0 ? A[(i) >> 2].x : ((i) & 3) == 1 ? A[(i) >> 2].y \
                    : ((i) & 3) == 2 ? A[(i) >> 2].z : A[(i) >> 2].w)

// ---------------------------------------------------------------------------
// Kernel 1: prep_all — three independent block roles in ONE launch:
//   blocks 0..7   : FPS (batch = blk) + sampled-bg gather + ebb constants
//   block  8      : BN-folded weight prep (bf16 Wa', Wc', W2', bb1, bb2)
//   blocks 9..104 : fg_xyz passthrough copy (1 float4/thread)
// ebb is computed directly from w1/g1/v1/b1/m1 inside the FPS blocks, so no
// cross-block dependency exists.
// ---------------------------------------------------------------------------
__global__ __launch_bounds__(1024, 4) void prep_all(
    const float* __restrict__ bg_xyz, const float* __restrict__ bg_feat,
    const float* __restrict__ w1, const float* __restrict__ g1, const float* __restrict__ b1,
    const float* __restrict__ m1, const float* __restrict__ v1,
    const float* __restrict__ w2, const float* __restrict__ g2, const float* __restrict__ b2,
    const float* __restrict__ m2, const float* __restrict__ v2,
    const float* __restrict__ fg_xyz, float* __restrict__ out_xyz,
    float* __restrict__ bb1, float* __restrict__ bb2,
    unsigned short* __restrict__ wa_bf, unsigned short* __restrict__ wc_bf,
    unsigned short* __restrict__ w2_bf,
    float* __restrict__ sbg, float* __restrict__ ebb) {
    const int blk = blockIdx.x;
    const int t = threadIdx.x;

    if (blk >= 9) { // ---- fg_xyz copy: 96 blocks x 1024 thr x 16B = 1.5 MB ----
        const int i = (blk - 9) * 1024 + t;
        ((float4*)out_xyz)[i] = ((const float4*)fg_xyz)[i];
        return;
    }

    if (blk == 8) { // ---- weight prep ----
        for (int i = t; i < 64 * 64; i += 1024) {
            const int o = i >> 6, c = i & 63;
            const float s1 = g1[o] / sqrtf(v1[o] + 1e-5f);
            const float s2 = g2[o] / sqrtf(v2[o] + 1e-5f);
            const float a = s1 * w1[o * 128 + c];
            const float bbv = s1 * w1[o * 128 + 64 + c];
            wa_bf[o * 64 + c] = f2bf(a);
            wc_bf[o * 64 + c] = f2bf(a + bbv);
            w2_bf[o * 64 + c] = f2bf(s2 * w2[o * 64 + c]);
        }
        if (t < 64) {
            const float s1 = g1[t] / sqrtf(v1[t] + 1e-5f);
            const float s2 = g2[t] / sqrtf(v2[t] + 1e-5f);
            bb1[t] = b1[t] - m1[t] * s1;
            bb2[t] = b2[t] - m2[t] * s2;
        }
        return;
    }

    // ---- FPS for batch b = blk: 1024 threads x 16 points, float4 loads ----
    const int b = blk;
    const float* p = bg_xyz + (size_t)b * N_ * 3;

    float4 f4[12];
    {
        const float4* pv = (const float4*)p + t * 12; // 192B contiguous/thread
#pragma unroll
        for (int i = 0; i < 12; ++i) f4[i] = pv[i];
    }
    float px[16], py[16], pz[16], dist[16];
#pragma unroll
    for (int k = 0; k < 16; ++k) {
        px[k] = GETF(f4, 3 * k);
        py[k] = GETF(f4, 3 * k + 1);
        pz[k] = GETF(f4, 3 * k + 2);
        dist[k] = 1e10f;
    }

    __shared__ float s_best[16];
    __shared__ int s_bidx[16];
    __shared__ int s_last;
    __shared__ int s_idx[S_];
    __shared__ float sf[S_][64];
    int last = 0;
    if (t == 0) s_idx[0] = 0;

    for (int step = 1; step < S_; ++step) {
        const float lx = p[last * 3 + 0];
        const float ly = p[last * 3 + 1];
        const float lz = p[last * 3 + 2];
        float best = -1.0f;
        int bidx = 0;
#pragma unroll
        for (int k = 0; k < 16; ++k) {
            float dx = px[k] - lx, dy = py[k] - ly, dz = pz[k] - lz;
            float d = dx * dx + dy * dy + dz * dz;
            float nd = fminf(dist[k], d);
            dist[k] = nd;
            // strict >: keeps the LOWEST index within this thread (k ascending)
            if (nd > best) { best = nd; bidx = t * 16 + k; }
        }
        // wave(64) reduce; tie -> smaller index (jnp.argmax = first max)
#pragma unroll
        for (int off = 32; off > 0; off >>= 1) {
            float ob = __shfl_down(best, off, 64);
            int oi = __shfl_down(bidx, off, 64);
            if (ob > best || (ob == best && oi < bidx)) { best = ob; bidx = oi; }
        }
        if ((t & 63) == 0) { s_best[t >> 6] = best; s_bidx[t >> 6] = bidx; }
        __syncthreads();
        if (t == 0) {
            float bb = s_best[0];
            int bi = s_bidx[0];
#pragma unroll
            for (int w = 1; w < 16; ++w) {
                if (s_best[w] > bb || (s_best[w] == bb && s_bidx[w] < bi)) {
                    bb = s_best[w];
                    bi = s_bidx[w];
                }
            }
            s_last = bi;
            s_idx[step] = bi;
        }
        __syncthreads();
        last = s_last;
        __syncthreads(); // protect s_best from next-iteration overwrite
    }

    // ---- sbg gather + ebb = s1.*(W1b @ sbg) + bb1, computed from raw w1 ----
    __syncthreads();
    if (t < S_ * 64) {
        const int j = t >> 6, c = t & 63;
        sf[j][c] = bg_feat[(size_t)b * C_ * N_ + (size_t)c * N_ + s_idx[j]];
    }
    __syncthreads();
    if (t < S_ * 64) {
        const int j = t >> 6, o = t & 63;
        const float s1 = g1[o] * rsqrtf(v1[o] + 1e-5f);
        const float4* wr = (const float4*)&w1[o * 128 + 64];
        float acc = 0.f;
#pragma unroll
        for (int c4 = 0; c4 < 16; ++c4) {
            float4 wv = wr[c4];
            acc += wv.x * sf[j][c4 * 4 + 0] + wv.y * sf[j][c4 * 4 + 1] +
                   wv.z * sf[j][c4 * 4 + 2] + wv.w * sf[j][c4 * 4 + 3];
        }
        sbg[(b * S_ + j) * 64 + o] = sf[j][o];
        ebb[(b * S_ + j) * 64 + o] = s1 * acc + (b1[o] - m1[o] * s1);
    }
}

// ---------------------------------------------------------------------------
// Kernel 2: main fused MLP, v3.
//  - F tile staged as f32 [c][n] via async global_load_lds (16B/lane, 4
//    instrs/thread, contiguous 1KB/wave bursts). No VGPR round-trip, no
//    transpose pass, no bf16 Ft buffer.
//  - ONE __syncthreads. Wave w owns 16 columns, computes all 64 channels.
//  - B-frags of F built once from LDS with packed bf16 cvt.
//  - Per-slice H: C-layout -> wave-private Ht (dbuf) -> B-frag (same-wave
//    LDS ordering, no barrier).
//  - Slice constants (ebb/sbg) read per-slice from LDS (not held in VGPRs).
//  - s=0 epilogue multiplier = exact f32 F from LDS.
// MFMA layouts (HW-verified): A[m=lane&15][k=(lane>>4)*8+j];
// C/D: col=lane&15, row=(lane>>4)*4+reg.
// ---------------------------------------------------------------------------
#define FP 64  // Flds pitch (floats) — forced by global_load_lds contiguity
#define HP 72  // Ht pitch (shorts): 2-way (free) bank aliasing on b64/b128

__global__ __launch_bounds__(256) void fusion_main(
    const float* __restrict__ fg_feat,
    const unsigned short* __restrict__ wa_bf, const unsigned short* __restrict__ wc_bf,
    const unsigned short* __restrict__ w2_bf,
    const float* __restrict__ bb1g, const float* __restrict__ bb2g,
    const float* __restrict__ ebbg, const float* __restrict__ sbgg,
    float* __restrict__ out) {
    __shared__ __align__(16) float Flds[64 * FP];            // 16 KB f32 F tile [c][n]
    __shared__ __align__(16) unsigned short Ht[2][4][16 * HP]; // 18 KB
    __shared__ __align__(16) float cEbb[S_ * 64];
    __shared__ __align__(16) float cSbg[S_ * 64];
    __shared__ __align__(16) float cBb1[64];
    __shared__ __align__(16) float cBb2[64];

    const int t = threadIdx.x;
    const int b = blockIdx.y;
    const int n0 = blockIdx.x * 64;
    const float* Fg = fg_feat + (size_t)b * C_ * N_ + n0;

    const int lane = t & 63;
    const int w = t >> 6;

    // ---- async stage F tile: round r, wave w -> c rows [r*16+w*4, +4) ----
    {
        const int crow = lane >> 4;  // row within the 4-row group
        const int nq = lane & 15;    // 16B chunk within a 256B row
#pragma unroll
        for (int r = 0; r < 4; ++r) {
            const int c = r * 16 + w * 4;
            const float* gsrc = Fg + (size_t)(c + crow) * N_ + nq * 4;
            // LDS dest is wave-uniform base + lane*16 == Flds[c][0] onward
            __builtin_amdgcn_global_load_lds(
                (const __attribute__((address_space(1))) unsigned int*)gsrc,
                (__attribute__((address_space(3))) unsigned int*)&Flds[c * FP],
                16, 0, 0);
        }
    }

    // ---- stage per-(b,slice) constants into LDS ----
    for (int i = t; i < S_ * 64; i += 256) {
        cEbb[i] = ebbg[b * (S_ * 64) + i];
        cSbg[i] = sbgg[b * (S_ * 64) + i];
    }
    if (t < 64) { cBb1[t] = bb1g[t]; cBb2[t] = bb2g[t]; }

    const int m = lane & 15;  // B col / D col
    const int q = lane >> 4;  // k-chunk / D row-group
    const int nrow = w * 16 + m;

    // W2 A-frags: persistent (used in all 6 slices), L2-resident loads
    v8bf aW2[4][2];
#pragma unroll
    for (int ob = 0; ob < 4; ++ob)
#pragma unroll
        for (int ks = 0; ks < 2; ++ks)
            aW2[ob][ks] = *(const v8bf*)&w2_bf[(ob * 16 + m) * 64 + ks * 32 + q * 8];

    __syncthreads(); // the ONLY barrier: Flds + constants ready

    // ---- build B-frags of F (once) with packed bf16 cvt ----
    v8bf bF[2];
#pragma unroll
    for (int ks = 0; ks < 2; ++ks) {
        unsigned int uu[4];
#pragma unroll
        for (int jp = 0; jp < 4; ++jp) {
            const int c = ks * 32 + q * 8 + jp * 2;
            float2 fp2;
            fp2.x = Flds[c * FP + nrow];
            fp2.y = Flds[(c + 1) * FP + nrow];
            __hip_bfloat162 h2 = __float22bfloat162_rn(fp2);
            __builtin_memcpy(&uu[jp], &h2, 4);
        }
        __builtin_memcpy(&bF[ks], uu, 16);
    }

    // ---- GEMM1: U = Wa'.F (slices>=1), U0 = Wc'.F (slice 0) ----
    v4f U[4], U0[4];
#pragma unroll
    for (int ob = 0; ob < 4; ++ob) {
        v8bf a0 = *(const v8bf*)&wa_bf[(ob * 16 + m) * 64 + q * 8];
        v8bf a1 = *(const v8bf*)&wa_bf[(ob * 16 + m) * 64 + 32 + q * 8];
        v4f z = {0.f, 0.f, 0.f, 0.f};
        z = __builtin_amdgcn_mfma_f32_16x16x32_bf16(a0, bF[0], z, 0, 0, 0);
        U[ob] = __builtin_amdgcn_mfma_f32_16x16x32_bf16(a1, bF[1], z, 0, 0, 0);
        v8bf c0 = *(const v8bf*)&wc_bf[(ob * 16 + m) * 64 + q * 8];
        v8bf c1 = *(const v8bf*)&wc_bf[(ob * 16 + m) * 64 + 32 + q * 8];
        v4f z2 = {0.f, 0.f, 0.f, 0.f};
        z2 = __builtin_amdgcn_mfma_f32_16x16x32_bf16(c0, bF[0], z2, 0, 0, 0);
        U0[ob] = __builtin_amdgcn_mfma_f32_16x16x32_bf16(c1, bF[1], z2, 0, 0, 0);
    }

    v4f acc[4];
#pragma unroll
    for (int ob = 0; ob < 4; ++ob) acc[ob] = (v4f){0.f, 0.f, 0.f, 0.f};

#pragma unroll
    for (int s = 0; s < 6; ++s) {
        unsigned short* h = &Ht[s & 1][w][0]; // wave-private, dbuf on parity

        // H (C-layout) -> wave-private Ht[n16][c], packed bf16 cvt
#pragma unroll
        for (int ob = 0; ob < 4; ++ob) {
            const int o4 = ob * 16 + 4 * q;
            v4f u, cv;
            if (s == 0) { u = U0[ob]; cv = *(const v4f*)&cBb1[o4]; }
            else        { u = U[ob];  cv = *(const v4f*)&cEbb[(s - 1) * 64 + o4]; }
            float2 e01, e23;
            e01.x = fmaxf(u[0] + cv[0], 0.f);
            e01.y = fmaxf(u[1] + cv[1], 0.f);
            e23.x = fmaxf(u[2] + cv[2], 0.f);
            e23.y = fmaxf(u[3] + cv[3], 0.f);
            __hip_bfloat162 h01 = __float22bfloat162_rn(e01);
            __hip_bfloat162 h23 = __float22bfloat162_rn(e23);
            unsigned int lo, hi;
            __builtin_memcpy(&lo, &h01, 4);
            __builtin_memcpy(&hi, &h23, 4);
            unsigned long long vv = (unsigned long long)lo | ((unsigned long long)hi << 32);
            *(unsigned long long*)&h[m * HP + o4] = vv;
        }

        // read B-frags of H (same wave wrote them; per-wave LDS ordering)
        v8bf hb0 = *(const v8bf*)&h[m * HP + q * 8];
        v8bf hb1 = *(const v8bf*)&h[m * HP + 32 + q * 8];

        // GEMM2 + epilogue: acc += relu(p + bb2) * multiplier
#pragma unroll
        for (int ob = 0; ob < 4; ++ob) {
            v4f z = {0.f, 0.f, 0.f, 0.f};
            z = __builtin_amdgcn_mfma_f32_16x16x32_bf16(aW2[ob][0], hb0, z, 0, 0, 0);
            v4f p4 = __builtin_amdgcn_mfma_f32_16x16x32_bf16(aW2[ob][1], hb1, z, 0, 0, 0);

            const int o4 = ob * 16 + 4 * q;
            const v4f b2v = *(const v4f*)&cBb2[o4];
            if (s == 0) {
#pragma unroll
                for (int r = 0; r < 4; ++r) {
                    float wgt = fmaxf(p4[r] + b2v[r], 0.f);
                    acc[ob][r] += wgt * Flds[(o4 + r) * FP + nrow]; // exact f32 F
                }
            } else {
                const v4f sb = *(const v4f*)&cSbg[(s - 1) * 64 + o4];
#pragma unroll
                for (int r = 0; r < 4; ++r) {
                    float wgt = fmaxf(p4[r] + b2v[r], 0.f);
                    acc[ob][r] += wgt * sb[r];
                }
            }
        }
    }

    // store: out[b][o][n], o = ob*16+4q+r, n = n0 + w*16 + m
#pragma unroll
    for (int ob = 0; ob < 4; ++ob)
#pragma unroll
        for (int r = 0; r < 4; ++r)
            out[(size_t)b * C_ * N_ + (size_t)(ob * 16 + 4 * q + r) * N_ + (n0 + w * 16 + m)] =
                acc[ob][r];
}

// ---------------------------------------------------------------------------
extern "C" void kernel_launch(void* const* d_in, const int* in_sizes, int n_in,
                              void* d_out, int out_size, void* d_ws, size_t ws_size,
                              hipStream_t stream) {
    const float* fg_xyz = (const float*)d_in[0];
    const float* fg_feat = (const float*)d_in[1];
    const float* bg_xyz = (const float*)d_in[2];
    const float* bg_feat = (const float*)d_in[3];
    const float* w1 = (const float*)d_in[4];
    const float* g1 = (const float*)d_in[5];
    const float* b1 = (const float*)d_in[6];
    const float* m1 = (const float*)d_in[7];
    const float* v1 = (const float*)d_in[8];
    const float* w2 = (const float*)d_in[9];
    const float* g2 = (const float*)d_in[10];
    const float* b2 = (const float*)d_in[11];
    const float* m2 = (const float*)d_in[12];
    const float* v2 = (const float*)d_in[13];

    // workspace layout (float units)
    float* ws = (float*)d_ws;
    float* ebb = ws;                        // 2560
    float* sbg = ebb + 2560;                // 2560
    float* bb1 = sbg + 2560;                // 64
    float* bb2 = bb1 + 64;                  // 64
    unsigned short* wa_bf = (unsigned short*)(bb2 + 64); // 4096 shorts
    unsigned short* wc_bf = wa_bf + 4096;
    unsigned short* w2_bf = wc_bf + 4096;

    float* out_feats = (float*)d_out + (size_t)B_ * N_ * 3;

    // node 1: FPS+sbg+ebb (blocks 0..7) | weight prep (8) | xyz copy (9..104)
    prep_all<<<105, 1024, 0, stream>>>(bg_xyz, bg_feat,
                                       w1, g1, b1, m1, v1, w2, g2, b2, m2, v2,
                                       fg_xyz, (float*)d_out,
                                       bb1, bb2, wa_bf, wc_bf, w2_bf, sbg, ebb);
    // node 2: fused MLP
    fusion_main<<<dim3(N_ / 64, B_), 256, 0, stream>>>(
        fg_feat, wa_bf, wc_bf, w2_bf, bb1, bb2, ebb, sbg, out_feats);
}